// Round 6
// baseline (145.338 us; speedup 1.0000x reference)
//
#include <hip/hip_runtime.h>
#include <cstdint>

// ---------------------------------------------------------------------------
// TwinTTL collapsed pipeline (6 dispatches):
//   k_front : inputs -> h (B x 64); conv weights repacked in-kernel to LDS
//             [315 MB read @ ~2.7 TB/s = chip read-path ceiling; done]
//   k_gram  : H2 = h^T h partials, hsum partials (256 blocks)
//   k_gred1 : 256 partials -> 8 group partials (136 blocks, depth 32)
//   k_small1: per-p (q,k,v): reduce 8->H2, s2_p = Wp H2 Wp^T + rank-1 (3 blocks)
//   k_small2: remaining serial 64x64 algebra -> Wo, bo (1 block)
//   k_out   : o = h@Wo + bo; LayerNorm; SiLU; dot(out_w) -> out (B)
// ---------------------------------------------------------------------------

// ---------------- k_front: inputs -> h  (R1 config, best measured 116us) ----
// 16 lanes per batch, 4 batches per wave, 4 waves per block, grid 2048.
// Weights repacked [o][c][k] -> [o][k*3+c] straight into LDS (L2-hot gather,
// ~29 scalar loads/thread, overlapped with fw/hb preamble). Global loads in
// the main loop are pure streaming input reads, batched 8-deep.
// Empirically at the chip read-path ceiling: occupancy 20/40/82% all gave
// ~2.5-2.7 TB/s consumption -> concurrency-independent limit. Do not touch.
__global__ void __launch_bounds__(256) k_front(
    const float* __restrict__ in1, const float* __restrict__ in2,
    const float* __restrict__ in3, const float* __restrict__ in4,
    const float* __restrict__ wl, const float* __restrict__ wm,
    const float* __restrict__ wsx,
    const float* __restrict__ bl, const float* __restrict__ bm,
    const float* __restrict__ bs_,
    const float* __restrict__ fc1w, const float* __restrict__ fc1b,
    float* __restrict__ hout)
{
  __shared__ __align__(16) float wsh[7200];
  for (int i = threadIdx.x; i < 4500; i += 256) {
    int o = i / 1500, e = i % 1500, k = e / 3, c = e % 3;
    wsh[i] = wl[o * 1500 + c * 500 + k];
  }
  for (int i = threadIdx.x; i < 2250; i += 256) {
    int o = i / 750, e = i % 750, k = e / 3, c = e % 3;
    wsh[4500 + i] = wm[o * 750 + c * 250 + k];
  }
  for (int i = threadIdx.x; i < 450; i += 256) {
    int o = i / 150, e = i % 150, k = e / 3, c = e % 3;
    wsh[6750 + i] = wsx[o * 150 + c * 50 + k];
  }

  const int l   = threadIdx.x & 63;
  const int w   = threadIdx.x >> 6;
  const int sub = l >> 4;
  const int t   = l & 15;
  const int b0  = blockIdx.x * 16 + w * 4;
  const size_t b = (size_t)(b0 + sub);

  float fw[12];
  #pragma unroll
  for (int i = 0; i < 12; ++i) fw[i] = fc1w[l * 12 + i];
  float hb = fc1b[l] + ((l & 1) ? 1.0f : 0.0f);   // + pe0
  hb += bl[0]*fw[0] + bl[1]*fw[1] + bl[2]*fw[2]
      + bm[0]*fw[3] + bm[1]*fw[4] + bm[2]*fw[5]
      + bs_[0]*fw[6] + bs_[1]*fw[7] + bs_[2]*fw[8];

  __syncthreads();

  float a0=0,a1=0,a2=0,a3=0,a4=0,a5=0,a6=0,a7=0,a8=0;

  { // input1: 375 float4 groups per row
    const float4* r  = (const float4*)(in1 + b * 1500);
    const float4* u0 = (const float4*)(wsh);
    const float4* u1 = (const float4*)(wsh + 1500);
    const float4* u2 = (const float4*)(wsh + 3000);
    #pragma unroll
    for (int c = 0; c < 2; ++c) {
      float4 vb[8];
      #pragma unroll
      for (int j = 0; j < 8; ++j) vb[j] = r[t + 16*(c*8 + j)];
      #pragma unroll
      for (int j = 0; j < 8; ++j) {
        const int g = t + 16*(c*8 + j);
        float4 v = vb[j], w0 = u0[g], w1 = u1[g], w2 = u2[g];
        a0 += v.x*w0.x + v.y*w0.y + v.z*w0.z + v.w*w0.w;
        a1 += v.x*w1.x + v.y*w1.y + v.z*w1.z + v.w*w1.w;
        a2 += v.x*w2.x + v.y*w2.y + v.z*w2.z + v.w*w2.w;
      }
    }
    {
      float4 vb[7];
      #pragma unroll
      for (int j = 0; j < 7; ++j) vb[j] = r[t + 16*(16 + j)];
      #pragma unroll
      for (int j = 0; j < 7; ++j) {
        const int g = t + 16*(16 + j);
        float4 v = vb[j], w0 = u0[g], w1 = u1[g], w2 = u2[g];
        a0 += v.x*w0.x + v.y*w0.y + v.z*w0.z + v.w*w0.w;
        a1 += v.x*w1.x + v.y*w1.y + v.z*w1.z + v.w*w1.w;
        a2 += v.x*w2.x + v.y*w2.y + v.z*w2.z + v.w*w2.w;
      }
    }
    if (t < 7) {
      const int g = 368 + t;
      float4 v = r[g], w0 = u0[g], w1 = u1[g], w2 = u2[g];
      a0 += v.x*w0.x + v.y*w0.y + v.z*w0.z + v.w*w0.w;
      a1 += v.x*w1.x + v.y*w1.y + v.z*w1.z + v.w*w1.w;
      a2 += v.x*w2.x + v.y*w2.y + v.z*w2.z + v.w*w2.w;
    }
  }

  { // input2: 375 float2 groups per row
    const float2* r  = (const float2*)(in2 + b * 750);
    const float2* u0 = (const float2*)(wsh + 4500);
    const float2* u1 = (const float2*)(wsh + 5250);
    const float2* u2 = (const float2*)(wsh + 6000);
    #pragma unroll
    for (int c = 0; c < 2; ++c) {
      float2 vb[8];
      #pragma unroll
      for (int j = 0; j < 8; ++j) vb[j] = r[t + 16*(c*8 + j)];
      #pragma unroll
      for (int j = 0; j < 8; ++j) {
        const int g = t + 16*(c*8 + j);
        float2 v = vb[j], w0 = u0[g], w1 = u1[g], w2 = u2[g];
        a3 += v.x*w0.x + v.y*w0.y;
        a4 += v.x*w1.x + v.y*w1.y;
        a5 += v.x*w2.x + v.y*w2.y;
      }
    }
    {
      float2 vb[7];
      #pragma unroll
      for (int j = 0; j < 7; ++j) vb[j] = r[t + 16*(16 + j)];
      #pragma unroll
      for (int j = 0; j < 7; ++j) {
        const int g = t + 16*(16 + j);
        float2 v = vb[j], w0 = u0[g], w1 = u1[g], w2 = u2[g];
        a3 += v.x*w0.x + v.y*w0.y;
        a4 += v.x*w1.x + v.y*w1.y;
        a5 += v.x*w2.x + v.y*w2.y;
      }
    }
    if (t < 7) {
      const int g = 368 + t;
      float2 v = r[g], w0 = u0[g], w1 = u1[g], w2 = u2[g];
      a3 += v.x*w0.x + v.y*w0.y;
      a4 += v.x*w1.x + v.y*w1.y;
      a5 += v.x*w2.x + v.y*w2.y;
    }
  }

  { // input3: 75 float2 groups per row
    const float2* r  = (const float2*)(in3 + b * 150);
    const float2* u0 = (const float2*)(wsh + 6750);
    const float2* u1 = (const float2*)(wsh + 6900);
    const float2* u2 = (const float2*)(wsh + 7050);
    {
      float2 vb[4];
      #pragma unroll
      for (int j = 0; j < 4; ++j) vb[j] = r[t + 16*j];
      #pragma unroll
      for (int j = 0; j < 4; ++j) {
        const int g = t + 16*j;
        float2 v = vb[j], w0 = u0[g], w1 = u1[g], w2 = u2[g];
        a6 += v.x*w0.x + v.y*w0.y;
        a7 += v.x*w1.x + v.y*w1.y;
        a8 += v.x*w2.x + v.y*w2.y;
      }
    }
    if (t < 11) {
      const int g = 64 + t;
      float2 v = r[g], w0 = u0[g], w1 = u1[g], w2 = u2[g];
      a6 += v.x*w0.x + v.y*w0.y;
      a7 += v.x*w1.x + v.y*w1.y;
      a8 += v.x*w2.x + v.y*w2.y;
    }
  }

  #pragma unroll
  for (int m = 1; m <= 8; m <<= 1) {
    a0 += __shfl_xor(a0, m, 64); a1 += __shfl_xor(a1, m, 64);
    a2 += __shfl_xor(a2, m, 64); a3 += __shfl_xor(a3, m, 64);
    a4 += __shfl_xor(a4, m, 64); a5 += __shfl_xor(a5, m, 64);
    a6 += __shfl_xor(a6, m, 64); a7 += __shfl_xor(a7, m, 64);
    a8 += __shfl_xor(a8, m, 64);
  }
  #pragma unroll
  for (int q = 0; q < 4; ++q) {
    float c0 = __shfl(a0, q*16, 64), c1 = __shfl(a1, q*16, 64), c2 = __shfl(a2, q*16, 64);
    float c3 = __shfl(a3, q*16, 64), c4 = __shfl(a4, q*16, 64), c5 = __shfl(a5, q*16, 64);
    float c6 = __shfl(a6, q*16, 64), c7 = __shfl(a7, q*16, 64), c8 = __shfl(a8, q*16, 64);
    int bb = b0 + q;
    const float* p4 = in4 + (size_t)bb * 3;
    float hv = hb + c0*fw[0] + c1*fw[1] + c2*fw[2] + c3*fw[3] + c4*fw[4]
                  + c5*fw[5] + c6*fw[6] + c7*fw[7] + c8*fw[8]
                  + p4[0]*fw[9] + p4[1]*fw[10] + p4[2]*fw[11];
    hout[(size_t)bb * 64 + l] = hv;
  }
}

// ---------------- k_gram: partial H2 = h^T h, hsum --------------------------
__global__ void __launch_bounds__(256) k_gram(const float* __restrict__ h,
                                              float* __restrict__ part) {
  __shared__ float hs[64][64];
  const int tid = threadIdx.x;
  const int r0 = (tid >> 4) << 2, c0 = (tid & 15) << 2;
  float acc[4][4] = {{0.f}};
  float sv = 0.f;
  for (int tile = 0; tile < 2; ++tile) {
    __syncthreads();
    const size_t trow = (size_t)(blockIdx.x * 2 + tile) * 64;
    const float4* src = (const float4*)(h + trow * 64);
    #pragma unroll
    for (int i = 0; i < 4; ++i) ((float4*)hs)[tid + 256*i] = src[tid + 256*i];
    __syncthreads();
    for (int k = 0; k < 64; ++k) {
      float4 av = *(const float4*)&hs[k][r0];
      float4 bv = *(const float4*)&hs[k][c0];
      float ar[4] = {av.x,av.y,av.z,av.w}, br[4] = {bv.x,bv.y,bv.z,bv.w};
      #pragma unroll
      for (int i = 0; i < 4; ++i)
        #pragma unroll
        for (int j = 0; j < 4; ++j) acc[i][j] += ar[i]*br[j];
    }
    if (tid < 64) { for (int k = 0; k < 64; ++k) sv += hs[k][tid]; }
  }
  float* dst = part + (size_t)blockIdx.x * 4160;
  #pragma unroll
  for (int i = 0; i < 4; ++i)
    *(float4*)&dst[(r0+i)*64 + c0] = make_float4(acc[i][0], acc[i][1], acc[i][2], acc[i][3]);
  if (tid < 64) dst[4096 + tid] = sv;
}

// ---------------- k_gred1: 256 partials -> 8 group partials -----------------
__global__ void k_gred1(const float* __restrict__ part, float* __restrict__ part2) {
  const int g = blockIdx.x % 17;
  const int s = blockIdx.x / 17;          // 0..7
  const int e = g * 256 + threadIdx.x;
  if (e >= 4160) return;
  float sum = 0.f;
  const float* p0 = part + (size_t)(s * 32) * 4160 + e;
  #pragma unroll 8
  for (int p = 0; p < 32; ++p) sum += p0[(size_t)p * 4160];
  part2[(size_t)s * 4160 + e] = sum;
}

// ---------------- k_small1/2: the 64x64 algebra -----------------------------
#define MM_TILE(DST, SA, SB, OPEQ)                                             \
  for (int k = 0; k < 64; ++k) {                                               \
    float4 av = *(const float4*)&SA[k][r0];                                    \
    float4 bv = *(const float4*)&SB[k][c0];                                    \
    float ar_[4] = {av.x,av.y,av.z,av.w};                                      \
    float br_[4] = {bv.x,bv.y,bv.z,bv.w};                                      \
    _Pragma("unroll") for (int i_ = 0; i_ < 4; ++i_)                           \
    _Pragma("unroll") for (int j_ = 0; j_ < 4; ++j_)                           \
      DST[i_][j_] OPEQ ar_[i_]*br_[j_];                                        \
  }
#define STAGE_N(DSTBUF, SRC) for (int i = threadIdx.x; i < 1024; i += 256) {   \
    int r_ = i >> 4, c_ = (i & 15) << 2;                                       \
    *(float4*)&DSTBUF[r_][c_] = ((const float4*)(SRC))[i]; }
#define STAGE_T(DSTBUF, SRC) for (int i = threadIdx.x; i < 4096; i += 256) {   \
    int r_ = i >> 6, k_ = i & 63; DSTBUF[k_][r_] = (SRC)[i]; }

// k_small1: one block per p in {q,k,v}. Reduces the 8 group partials to H2
// (same s=0..7 order as the old k_gred2 -> bit-identical), then
// s2_p = Wp H2 Wp^T + rank-1, alpha_p.
__global__ void __launch_bounds__(256) k_small1(
    const float* __restrict__ part2,
    const float* __restrict__ qw, const float* __restrict__ qb_,
    const float* __restrict__ kw, const float* __restrict__ kb_,
    const float* __restrict__ vw, const float* __restrict__ vb_,
    float* __restrict__ s2p)
{
  __shared__ float BA[64][68];
  __shared__ float BB[64][68];
  __shared__ float BC[64][68];
  __shared__ float sm[128];   // 0:hsum 64:alpha
  const int tid = threadIdx.x;
  const int r0 = (tid >> 4) << 2;
  const int c0 = (tid & 15) << 2;
  const int p  = blockIdx.x;
  const float* Wp = (p == 0) ? qw : (p == 1) ? kw : vw;
  const float* bp = (p == 0) ? qb_ : (p == 1) ? kb_ : vb_;

  // H2 = sum_{s=0..7} part2[s] -> BC ; hsum likewise -> sm[0..63]
  for (int i = tid; i < 1024; i += 256) {
    int r_ = i >> 4, c_ = (i & 15) << 2;
    float4 a = ((const float4*)(part2))[i];
    #pragma unroll
    for (int s = 1; s < 8; ++s) {
      float4 v = ((const float4*)(part2 + (size_t)s * 4160))[i];
      a.x += v.x; a.y += v.y; a.z += v.z; a.w += v.w;
    }
    *(float4*)&BC[r_][c_] = a;
  }
  if (tid < 64) {
    float s = 0.f;
    #pragma unroll
    for (int g = 0; g < 8; ++g) s += part2[(size_t)g * 4160 + 4096 + tid];
    sm[tid] = s;
  }
  STAGE_T(BA, Wp);                         // BA[k][r] = Wp[r][k]
  __syncthreads();
  if (tid < 64) {                          // alpha_p = Wp @ hsum
    float s = 0.f;
    for (int k = 0; k < 64; ++k) s += BA[k][tid] * sm[k];
    sm[64 + tid] = s;
    s2p[(size_t)p * 4160 + 4096 + tid] = s;
  }
  float g4[4][4] = {{0.f}};
  MM_TILE(g4, BA, BC, +=);                 // G = Wp @ H2
  #pragma unroll
  for (int i = 0; i < 4; ++i)
    #pragma unroll
    for (int j = 0; j < 4; ++j) BB[c0+j][r0+i] = g4[i][j];   // G^T
  __syncthreads();
  float s2[4][4] = {{0.f}};
  MM_TILE(s2, BB, BA, +=);                 // s2 = G @ Wp^T
  {                                        // rank-1 terms
    float ar[4], ac[4], br[4], bc4[4];
    #pragma unroll
    for (int i = 0; i < 4; ++i) { ar[i] = sm[64+r0+i]; br[i] = bp[r0+i]; }
    #pragma unroll
    for (int j = 0; j < 4; ++j) { ac[j] = sm[64+c0+j]; bc4[j] = bp[c0+j]; }
    #pragma unroll
    for (int i = 0; i < 4; ++i)
      #pragma unroll
      for (int j = 0; j < 4; ++j)
        s2[i][j] += ar[i]*bc4[j] + br[i]*ac[j] + 32768.f*br[i]*bc4[j];
  }
  #pragma unroll
  for (int i = 0; i < 4; ++i)
    *(float4*)&s2p[(size_t)p * 4160 + (r0+i)*64 + c0] =
        make_float4(s2[i][0], s2[i][1], s2[i][2], s2[i][3]);
}

// k_small2: S2 = sum_p s2_p, then the serial chain -> Wo, bo
__global__ void __launch_bounds__(256) k_small2(
    const float* __restrict__ s2p,
    const float* __restrict__ qb_, const float* __restrict__ kb_,
    const float* __restrict__ vb_,
    const float* __restrict__ tk, const float* __restrict__ tv_,
    const float* __restrict__ tq, const float* __restrict__ lw,
    const float* __restrict__ lb_, const float* __restrict__ vw,
    float* __restrict__ wobo)
{
  __shared__ float BA[64][68];
  __shared__ float BB[64][68];
  __shared__ float BC[64][68];
  __shared__ float sm[512];   // 256:sum_s 320:w1 384:lb1 448:tvs
  const int tid = threadIdx.x;
  const int r0 = (tid >> 4) << 2;
  const int c0 = (tid & 15) << 2;

  for (int i = tid; i < 1024; i += 256) {
    int r_ = i >> 4, c_ = (i & 15) << 2;
    float4 v0 = ((const float4*)(s2p))[i];
    float4 v1 = ((const float4*)(s2p + 4160))[i];
    float4 v2 = ((const float4*)(s2p + 8320))[i];
    *(float4*)&BA[r_][c_] = make_float4(v0.x+v1.x+v2.x, v0.y+v1.y+v2.y,
                                        v0.z+v1.z+v2.z, v0.w+v1.w+v2.w);
  }
  STAGE_N(BC, tk);
  if (tid < 64) {
    float ss = s2p[4096 + tid] + s2p[4160 + 4096 + tid] + s2p[8320 + 4096 + tid]
             + 32768.f * (qb_[tid] + kb_[tid] + vb_[tid]);
    sm[256 + tid] = ss;
  }
  __syncthreads();
  if (tid < 64) {                          // w1 = t_k^T sum_s
    float s = 0.f;
    for (int k = 0; k < 64; ++k) s += BC[k][tid] * sm[256+k];
    sm[320 + tid] = s;
  }
  float y4[4][4] = {{0.f}};
  MM_TILE(y4, BA, BC, +=);                 // Y = S2 @ t_k
  __syncthreads();
  #pragma unroll
  for (int i = 0; i < 4; ++i)
    #pragma unroll
    for (int j = 0; j < 4; ++j) BB[r0+i][c0+j] = y4[i][j];       // Y
  STAGE_N(BA, tv_);                        // t_v (S2 dead)
  __syncthreads();
  if (tid < 64) {                          // tvs = t_v^T sum_s
    float s = 0.f;
    for (int k = 0; k < 64; ++k) s += BA[k][tid] * sm[256+k];
    sm[448 + tid] = s;
  }
  float core[4][4] = {{0.f}}, z4[4][4] = {{0.f}};
  for (int k = 0; k < 64; ++k) {           // core = -t_v^T Y ; Z = t_k^T Y
    float4 av1 = *(const float4*)&BA[k][r0];
    float4 av2 = *(const float4*)&BC[k][r0];
    float4 bv  = *(const float4*)&BB[k][c0];
    float a1_[4] = {av1.x,av1.y,av1.z,av1.w};
    float a2_[4] = {av2.x,av2.y,av2.z,av2.w};
    float b_[4]  = {bv.x,bv.y,bv.z,bv.w};
    #pragma unroll
    for (int i = 0; i < 4; ++i)
      #pragma unroll
      for (int j = 0; j < 4; ++j) { core[i][j] -= a1_[i]*b_[j]; z4[i][j] += a2_[i]*b_[j]; }
  }
  __syncthreads();
  #pragma unroll
  for (int i = 0; i < 4; ++i)
    #pragma unroll
    for (int j = 0; j < 4; ++j) BA[r0+i][c0+j] = z4[i][j];       // Z
  STAGE_T(BC, lw);                         // BC[k][r] = lw[r][k]
  __syncthreads();
  MM_TILE(core, BC, BA, +=);               // core += lw @ Z
  const float cg = 2.0f / 6291456.0f;      // 2 / (3B*64)
  float l1t[4][4];
  #pragma unroll
  for (int i = 0; i < 4; ++i) {
    float lbi = lb_[r0+i];
    #pragma unroll
    for (int j = 0; j < 4; ++j) {
      float gw  = cg * (core[i][j] + lbi * sm[320 + c0 + j]);
      float lwv = lw[(r0+i)*64 + (c0+j)];
      l1t[i][j] = lwv - 0.01f * gw / (fabsf(gw) + 1e-8f);
    }
  }
  __syncthreads();
  #pragma unroll
  for (int i = 0; i < 4; ++i)
    #pragma unroll
    for (int j = 0; j < 4; ++j) BB[c0+j][r0+i] = l1t[i][j];      // lw1^T
  if (tid < 64) {                          // gb -> lb1
    float s = 0.f;
    for (int c = 0; c < 64; ++c) s += lw[tid*64 + c] * sm[320 + c];
    float gb = cg * (s - sm[448 + tid] + 98304.f * lb_[tid]);
    sm[384 + tid] = lb_[tid] - 0.01f * gb / (fabsf(gb) + 1e-8f);
  }
  STAGE_T(BC, tq);                         // BC[k][r] = tq[r][k]
  __syncthreads();
  float u4[4][4] = {{0.f}};
  MM_TILE(u4, BC, BB, +=);                 // U = t_q @ lw1^T
  __syncthreads();
  #pragma unroll
  for (int i = 0; i < 4; ++i)
    #pragma unroll
    for (int j = 0; j < 4; ++j) BA[r0+i][c0+j] = u4[i][j];       // U
  STAGE_N(BC, vw);                         // v_w normal
  __syncthreads();
  float w4[4][4] = {{0.f}};
  MM_TILE(w4, BC, BA, +=);                 // Wo = v_w^T @ U
  #pragma unroll
  for (int i = 0; i < 4; ++i)
    *(float4*)&wobo[(r0+i)*64 + c0] = make_float4(w4[i][0], w4[i][1], w4[i][2], w4[i][3]);
  if (tid < 64) {                          // bo = v_b @ U + lb1
    float s = 0.f;
    for (int a = 0; a < 64; ++a) s += vb_[a] * BA[a][tid];
    wobo[4096 + tid] = s + sm[384 + tid];
  }
}

// ---------------- k_out: o = h@Wo + bo; LN; SiLU; dot(out_w) ----------------
__global__ void __launch_bounds__(128) k_out(
    const float* __restrict__ h, const float* __restrict__ wobo,
    const float* __restrict__ lng, const float* __restrict__ lnb,
    const float* __restrict__ outw, const float* __restrict__ outb,
    float* __restrict__ out)
{
  const size_t b = (size_t)blockIdx.x * 128 + threadIdx.x;
  const float* hr = h + b * 64;
  float o[64];
  #pragma unroll
  for (int j = 0; j < 64; ++j) o[j] = wobo[4096 + j];
  #pragma unroll 1
  for (int i = 0; i < 64; i += 4) {
    float4 hv = *(const float4*)(hr + i);
    const float* wr0 = wobo + (i+0)*64;
    const float* wr1 = wobo + (i+1)*64;
    const float* wr2 = wobo + (i+2)*64;
    const float* wr3 = wobo + (i+3)*64;
    #pragma unroll
    for (int j = 0; j < 64; ++j) o[j] += hv.x * wr0[j];
    #pragma unroll
    for (int j = 0; j < 64; ++j) o[j] += hv.y * wr1[j];
    #pragma unroll
    for (int j = 0; j < 64; ++j) o[j] += hv.z * wr2[j];
    #pragma unroll
    for (int j = 0; j < 64; ++j) o[j] += hv.w * wr3[j];
  }
  float mu = 0.f;
  #pragma unroll
  for (int j = 0; j < 64; ++j) mu += o[j];
  mu *= (1.0f/64.0f);
  float var = 0.f;
  #pragma unroll
  for (int j = 0; j < 64; ++j) { float d = o[j] - mu; var += d*d; }
  var *= (1.0f/64.0f);
  float inv = rsqrtf(var + 1e-5f);
  float accv = outb[0];
  #pragma unroll
  for (int j = 0; j < 64; ++j) {
    float n = (o[j] - mu) * inv * lng[j] + lnb[j];
    float a = n / (1.0f + __expf(-n));
    accv += a * outw[j];
  }
  out[b] = accv;
}

// ---------------------------------------------------------------------------
extern "C" void kernel_launch(void* const* d_in, const int* in_sizes, int n_in,
                              void* d_out, int out_size, void* d_ws, size_t ws_size,
                              hipStream_t stream) {
  const float* in1  = (const float*)d_in[0];
  const float* in2  = (const float*)d_in[1];
  const float* in3  = (const float*)d_in[2];
  const float* in4  = (const float*)d_in[3];
  const float* w_l  = (const float*)d_in[4];
  const float* b_l  = (const float*)d_in[5];
  const float* w_m  = (const float*)d_in[6];
  const float* b_m  = (const float*)d_in[7];
  const float* w_s  = (const float*)d_in[8];
  const float* b_s  = (const float*)d_in[9];
  const float* fc1w = (const float*)d_in[10];
  const float* fc1b = (const float*)d_in[11];
  const float* q_w  = (const float*)d_in[12];
  const float* q_b  = (const float*)d_in[13];
  const float* k_w  = (const float*)d_in[14];
  const float* k_b  = (const float*)d_in[15];
  const float* v_w  = (const float*)d_in[16];
  const float* v_b  = (const float*)d_in[17];
  const float* t_k  = (const float*)d_in[18];
  const float* t_v  = (const float*)d_in[19];
  const float* t_q  = (const float*)d_in[20];
  const float* lw   = (const float*)d_in[21];
  const float* lb   = (const float*)d_in[22];
  const float* ln_g = (const float*)d_in[23];
  const float* ln_b = (const float*)d_in[24];
  const float* outw = (const float*)d_in[25];
  const float* outb = (const float*)d_in[26];

  float* ws    = (float*)d_ws;
  float* H     = ws;                      // 32768*64 = 2097152
  float* PART  = H + 2097152;             // 256*4160 = 1064960
  float* PART2 = PART + 1064960;          // 8*4160 = 33280
  float* S2P   = PART2 + 33280;           // 3*4160 = 12480
  float* WOBO  = S2P + 12480;             // 4160 (Wo + bo)

  k_front <<<2048, 256, 0, stream>>>(in1, in2, in3, in4, w_l, w_m, w_s,
                                     b_l, b_m, b_s, fc1w, fc1b, H);
  k_gram  <<<256,  256, 0, stream>>>(H, PART);
  k_gred1 <<<136,  256, 0, stream>>>(PART, PART2);
  k_small1<<<3,    256, 0, stream>>>(PART2, q_w, q_b, k_w, k_b, v_w, v_b, S2P);
  k_small2<<<1,    256, 0, stream>>>(S2P, q_b, k_b, v_b, t_k, t_v, t_q,
                                     lw, lb, v_w, WOBO);
  k_out   <<<256,  128, 0, stream>>>(H, WOBO, ln_g, ln_b, outw, outb,
                                     (float*)d_out);
}

// Round 7
// 140.976 us; speedup vs baseline: 1.0309x; 1.0309x over previous
//
#include <hip/hip_runtime.h>
#include <cstdint>

// ---------------------------------------------------------------------------
// TwinTTL collapsed pipeline (7 dispatches):
//   k_prep  : one-time conv-weight repack [o][c][k] -> [o][k*3+c] (29 blocks)
//   k_front : inputs -> h (B x 64); weights float4-copied WT->LDS
//             [315 MB read @ ~2.7 TB/s = chip read-path ceiling; done]
//   k_gram  : H2 = h^T h partials, hsum partials (256 blocks)
//   k_gred1 : 256 partials -> 8 group partials (136 blocks, depth 32)
//   k_small1: per-p (q,k,v): reduce 8->H2, s2_p = Wp H2 Wp^T + rank-1 (3 blocks)
//   k_small2: remaining serial 64x64 algebra -> Wo, bo (1 block)
//   k_out   : o = h@Wo + bo; LayerNorm; SiLU; dot(out_w) -> out (B)
// Lesson R6: repack inside k_front costs +9us (per-block div/mod gather);
// separate k_prep costs only ~2.5us total. Keep them split.
// ---------------------------------------------------------------------------

// ---------------- prep: repack conv weights to [o][k*3+c] contiguous -------
__global__ void k_prep(const float* __restrict__ wl, const float* __restrict__ wm,
                       const float* __restrict__ wsx, float* __restrict__ wt) {
  int tid = blockIdx.x * 256 + threadIdx.x;
  if (tid < 4500) {
    int o = tid / 1500, e = tid % 1500, k = e / 3, c = e % 3;
    wt[tid] = wl[o * 1500 + c * 500 + k];
  } else if (tid < 6750) {
    int r = tid - 4500; int o = r / 750, e = r % 750, k = e / 3, c = e % 3;
    wt[tid] = wm[o * 750 + c * 250 + k];
  } else if (tid < 7200) {
    int r = tid - 6750; int o = r / 150, e = r % 150, k = e / 3, c = e % 3;
    wt[tid] = wsx[o * 150 + c * 50 + k];
  }
}

// ---------------- k_front: inputs -> h  (R1/R5 config, measured 116.7us) ----
// 16 lanes per batch, 4 batches per wave, 4 waves per block, grid 2048.
// All weights staged WT->LDS via coalesced float4 copy; main-loop global
// loads are pure streaming input reads, batched 8-deep. Empirically at the
// chip read-path ceiling (occupancy 20/40/82% all gave ~2.5-2.7 TB/s).
__global__ void __launch_bounds__(256) k_front(
    const float* __restrict__ in1, const float* __restrict__ in2,
    const float* __restrict__ in3, const float* __restrict__ in4,
    const float* __restrict__ bl, const float* __restrict__ bm,
    const float* __restrict__ bs_,
    const float* __restrict__ fc1w, const float* __restrict__ fc1b,
    const float* __restrict__ wt, float* __restrict__ hout)
{
  __shared__ __align__(16) float wsh[7200];
  {
    const float4* s4 = (const float4*)wt;
    float4* d4 = (float4*)wsh;
    for (int i = threadIdx.x; i < 1800; i += 256) d4[i] = s4[i];
  }

  const int l   = threadIdx.x & 63;
  const int w   = threadIdx.x >> 6;
  const int sub = l >> 4;
  const int t   = l & 15;
  const int b0  = blockIdx.x * 16 + w * 4;
  const size_t b = (size_t)(b0 + sub);

  float fw[12];
  #pragma unroll
  for (int i = 0; i < 12; ++i) fw[i] = fc1w[l * 12 + i];
  float hb = fc1b[l] + ((l & 1) ? 1.0f : 0.0f);   // + pe0
  hb += bl[0]*fw[0] + bl[1]*fw[1] + bl[2]*fw[2]
      + bm[0]*fw[3] + bm[1]*fw[4] + bm[2]*fw[5]
      + bs_[0]*fw[6] + bs_[1]*fw[7] + bs_[2]*fw[8];

  __syncthreads();

  float a0=0,a1=0,a2=0,a3=0,a4=0,a5=0,a6=0,a7=0,a8=0;

  { // input1: 375 float4 groups per row
    const float4* r  = (const float4*)(in1 + b * 1500);
    const float4* u0 = (const float4*)(wsh);
    const float4* u1 = (const float4*)(wsh + 1500);
    const float4* u2 = (const float4*)(wsh + 3000);
    #pragma unroll
    for (int c = 0; c < 2; ++c) {
      float4 vb[8];
      #pragma unroll
      for (int j = 0; j < 8; ++j) vb[j] = r[t + 16*(c*8 + j)];
      #pragma unroll
      for (int j = 0; j < 8; ++j) {
        const int g = t + 16*(c*8 + j);
        float4 v = vb[j], w0 = u0[g], w1 = u1[g], w2 = u2[g];
        a0 += v.x*w0.x + v.y*w0.y + v.z*w0.z + v.w*w0.w;
        a1 += v.x*w1.x + v.y*w1.y + v.z*w1.z + v.w*w1.w;
        a2 += v.x*w2.x + v.y*w2.y + v.z*w2.z + v.w*w2.w;
      }
    }
    {
      float4 vb[7];
      #pragma unroll
      for (int j = 0; j < 7; ++j) vb[j] = r[t + 16*(16 + j)];
      #pragma unroll
      for (int j = 0; j < 7; ++j) {
        const int g = t + 16*(16 + j);
        float4 v = vb[j], w0 = u0[g], w1 = u1[g], w2 = u2[g];
        a0 += v.x*w0.x + v.y*w0.y + v.z*w0.z + v.w*w0.w;
        a1 += v.x*w1.x + v.y*w1.y + v.z*w1.z + v.w*w1.w;
        a2 += v.x*w2.x + v.y*w2.y + v.z*w2.z + v.w*w2.w;
      }
    }
    if (t < 7) {
      const int g = 368 + t;
      float4 v = r[g], w0 = u0[g], w1 = u1[g], w2 = u2[g];
      a0 += v.x*w0.x + v.y*w0.y + v.z*w0.z + v.w*w0.w;
      a1 += v.x*w1.x + v.y*w1.y + v.z*w1.z + v.w*w1.w;
      a2 += v.x*w2.x + v.y*w2.y + v.z*w2.z + v.w*w2.w;
    }
  }

  { // input2: 375 float2 groups per row
    const float2* r  = (const float2*)(in2 + b * 750);
    const float2* u0 = (const float2*)(wsh + 4500);
    const float2* u1 = (const float2*)(wsh + 5250);
    const float2* u2 = (const float2*)(wsh + 6000);
    #pragma unroll
    for (int c = 0; c < 2; ++c) {
      float2 vb[8];
      #pragma unroll
      for (int j = 0; j < 8; ++j) vb[j] = r[t + 16*(c*8 + j)];
      #pragma unroll
      for (int j = 0; j < 8; ++j) {
        const int g = t + 16*(c*8 + j);
        float2 v = vb[j], w0 = u0[g], w1 = u1[g], w2 = u2[g];
        a3 += v.x*w0.x + v.y*w0.y;
        a4 += v.x*w1.x + v.y*w1.y;
        a5 += v.x*w2.x + v.y*w2.y;
      }
    }
    {
      float2 vb[7];
      #pragma unroll
      for (int j = 0; j < 7; ++j) vb[j] = r[t + 16*(16 + j)];
      #pragma unroll
      for (int j = 0; j < 7; ++j) {
        const int g = t + 16*(16 + j);
        float2 v = vb[j], w0 = u0[g], w1 = u1[g], w2 = u2[g];
        a3 += v.x*w0.x + v.y*w0.y;
        a4 += v.x*w1.x + v.y*w1.y;
        a5 += v.x*w2.x + v.y*w2.y;
      }
    }
    if (t < 7) {
      const int g = 368 + t;
      float2 v = r[g], w0 = u0[g], w1 = u1[g], w2 = u2[g];
      a3 += v.x*w0.x + v.y*w0.y;
      a4 += v.x*w1.x + v.y*w1.y;
      a5 += v.x*w2.x + v.y*w2.y;
    }
  }

  { // input3: 75 float2 groups per row
    const float2* r  = (const float2*)(in3 + b * 150);
    const float2* u0 = (const float2*)(wsh + 6750);
    const float2* u1 = (const float2*)(wsh + 6900);
    const float2* u2 = (const float2*)(wsh + 7050);
    {
      float2 vb[4];
      #pragma unroll
      for (int j = 0; j < 4; ++j) vb[j] = r[t + 16*j];
      #pragma unroll
      for (int j = 0; j < 4; ++j) {
        const int g = t + 16*j;
        float2 v = vb[j], w0 = u0[g], w1 = u1[g], w2 = u2[g];
        a6 += v.x*w0.x + v.y*w0.y;
        a7 += v.x*w1.x + v.y*w1.y;
        a8 += v.x*w2.x + v.y*w2.y;
      }
    }
    if (t < 11) {
      const int g = 64 + t;
      float2 v = r[g], w0 = u0[g], w1 = u1[g], w2 = u2[g];
      a6 += v.x*w0.x + v.y*w0.y;
      a7 += v.x*w1.x + v.y*w1.y;
      a8 += v.x*w2.x + v.y*w2.y;
    }
  }

  #pragma unroll
  for (int m = 1; m <= 8; m <<= 1) {
    a0 += __shfl_xor(a0, m, 64); a1 += __shfl_xor(a1, m, 64);
    a2 += __shfl_xor(a2, m, 64); a3 += __shfl_xor(a3, m, 64);
    a4 += __shfl_xor(a4, m, 64); a5 += __shfl_xor(a5, m, 64);
    a6 += __shfl_xor(a6, m, 64); a7 += __shfl_xor(a7, m, 64);
    a8 += __shfl_xor(a8, m, 64);
  }
  #pragma unroll
  for (int q = 0; q < 4; ++q) {
    float c0 = __shfl(a0, q*16, 64), c1 = __shfl(a1, q*16, 64), c2 = __shfl(a2, q*16, 64);
    float c3 = __shfl(a3, q*16, 64), c4 = __shfl(a4, q*16, 64), c5 = __shfl(a5, q*16, 64);
    float c6 = __shfl(a6, q*16, 64), c7 = __shfl(a7, q*16, 64), c8 = __shfl(a8, q*16, 64);
    int bb = b0 + q;
    const float* p4 = in4 + (size_t)bb * 3;
    float hv = hb + c0*fw[0] + c1*fw[1] + c2*fw[2] + c3*fw[3] + c4*fw[4]
                  + c5*fw[5] + c6*fw[6] + c7*fw[7] + c8*fw[8]
                  + p4[0]*fw[9] + p4[1]*fw[10] + p4[2]*fw[11];
    hout[(size_t)bb * 64 + l] = hv;
  }
}

// ---------------- k_gram: partial H2 = h^T h, hsum --------------------------
__global__ void __launch_bounds__(256) k_gram(const float* __restrict__ h,
                                              float* __restrict__ part) {
  __shared__ float hs[64][64];
  const int tid = threadIdx.x;
  const int r0 = (tid >> 4) << 2, c0 = (tid & 15) << 2;
  float acc[4][4] = {{0.f}};
  float sv = 0.f;
  for (int tile = 0; tile < 2; ++tile) {
    __syncthreads();
    const size_t trow = (size_t)(blockIdx.x * 2 + tile) * 64;
    const float4* src = (const float4*)(h + trow * 64);
    #pragma unroll
    for (int i = 0; i < 4; ++i) ((float4*)hs)[tid + 256*i] = src[tid + 256*i];
    __syncthreads();
    for (int k = 0; k < 64; ++k) {
      float4 av = *(const float4*)&hs[k][r0];
      float4 bv = *(const float4*)&hs[k][c0];
      float ar[4] = {av.x,av.y,av.z,av.w}, br[4] = {bv.x,bv.y,bv.z,bv.w};
      #pragma unroll
      for (int i = 0; i < 4; ++i)
        #pragma unroll
        for (int j = 0; j < 4; ++j) acc[i][j] += ar[i]*br[j];
    }
    if (tid < 64) { for (int k = 0; k < 64; ++k) sv += hs[k][tid]; }
  }
  float* dst = part + (size_t)blockIdx.x * 4160;
  #pragma unroll
  for (int i = 0; i < 4; ++i)
    *(float4*)&dst[(r0+i)*64 + c0] = make_float4(acc[i][0], acc[i][1], acc[i][2], acc[i][3]);
  if (tid < 64) dst[4096 + tid] = sv;
}

// ---------------- k_gred1: 256 partials -> 8 group partials -----------------
__global__ void k_gred1(const float* __restrict__ part, float* __restrict__ part2) {
  const int g = blockIdx.x % 17;
  const int s = blockIdx.x / 17;          // 0..7
  const int e = g * 256 + threadIdx.x;
  if (e >= 4160) return;
  float sum = 0.f;
  const float* p0 = part + (size_t)(s * 32) * 4160 + e;
  #pragma unroll 8
  for (int p = 0; p < 32; ++p) sum += p0[(size_t)p * 4160];
  part2[(size_t)s * 4160 + e] = sum;
}

// ---------------- k_small1/2: the 64x64 algebra -----------------------------
#define MM_TILE(DST, SA, SB, OPEQ)                                             \
  for (int k = 0; k < 64; ++k) {                                               \
    float4 av = *(const float4*)&SA[k][r0];                                    \
    float4 bv = *(const float4*)&SB[k][c0];                                    \
    float ar_[4] = {av.x,av.y,av.z,av.w};                                      \
    float br_[4] = {bv.x,bv.y,bv.z,bv.w};                                      \
    _Pragma("unroll") for (int i_ = 0; i_ < 4; ++i_)                           \
    _Pragma("unroll") for (int j_ = 0; j_ < 4; ++j_)                           \
      DST[i_][j_] OPEQ ar_[i_]*br_[j_];                                        \
  }
#define STAGE_N(DSTBUF, SRC) for (int i = threadIdx.x; i < 1024; i += 256) {   \
    int r_ = i >> 4, c_ = (i & 15) << 2;                                       \
    *(float4*)&DSTBUF[r_][c_] = ((const float4*)(SRC))[i]; }
#define STAGE_T(DSTBUF, SRC) for (int i = threadIdx.x; i < 4096; i += 256) {   \
    int r_ = i >> 6, k_ = i & 63; DSTBUF[k_][r_] = (SRC)[i]; }

// k_small1: one block per p in {q,k,v}. Reduces the 8 group partials to H2
// (same s=0..7 order as the old k_gred2 -> bit-identical), then
// s2_p = Wp H2 Wp^T + rank-1, alpha_p.
__global__ void __launch_bounds__(256) k_small1(
    const float* __restrict__ part2,
    const float* __restrict__ qw, const float* __restrict__ qb_,
    const float* __restrict__ kw, const float* __restrict__ kb_,
    const float* __restrict__ vw, const float* __restrict__ vb_,
    float* __restrict__ s2p)
{
  __shared__ float BA[64][68];
  __shared__ float BB[64][68];
  __shared__ float BC[64][68];
  __shared__ float sm[128];   // 0:hsum 64:alpha
  const int tid = threadIdx.x;
  const int r0 = (tid >> 4) << 2;
  const int c0 = (tid & 15) << 2;
  const int p  = blockIdx.x;
  const float* Wp = (p == 0) ? qw : (p == 1) ? kw : vw;
  const float* bp = (p == 0) ? qb_ : (p == 1) ? kb_ : vb_;

  // H2 = sum_{s=0..7} part2[s] -> BC ; hsum likewise -> sm[0..63]
  for (int i = tid; i < 1024; i += 256) {
    int r_ = i >> 4, c_ = (i & 15) << 2;
    float4 a = ((const float4*)(part2))[i];
    #pragma unroll
    for (int s = 1; s < 8; ++s) {
      float4 v = ((const float4*)(part2 + (size_t)s * 4160))[i];
      a.x += v.x; a.y += v.y; a.z += v.z; a.w += v.w;
    }
    *(float4*)&BC[r_][c_] = a;
  }
  if (tid < 64) {
    float s = 0.f;
    #pragma unroll
    for (int g = 0; g < 8; ++g) s += part2[(size_t)g * 4160 + 4096 + tid];
    sm[tid] = s;
  }
  STAGE_T(BA, Wp);                         // BA[k][r] = Wp[r][k]
  __syncthreads();
  if (tid < 64) {                          // alpha_p = Wp @ hsum
    float s = 0.f;
    for (int k = 0; k < 64; ++k) s += BA[k][tid] * sm[k];
    sm[64 + tid] = s;
    s2p[(size_t)p * 4160 + 4096 + tid] = s;
  }
  float g4[4][4] = {{0.f}};
  MM_TILE(g4, BA, BC, +=);                 // G = Wp @ H2
  #pragma unroll
  for (int i = 0; i < 4; ++i)
    #pragma unroll
    for (int j = 0; j < 4; ++j) BB[c0+j][r0+i] = g4[i][j];   // G^T
  __syncthreads();
  float s2[4][4] = {{0.f}};
  MM_TILE(s2, BB, BA, +=);                 // s2 = G @ Wp^T
  {                                        // rank-1 terms
    float ar[4], ac[4], br[4], bc4[4];
    #pragma unroll
    for (int i = 0; i < 4; ++i) { ar[i] = sm[64+r0+i]; br[i] = bp[r0+i]; }
    #pragma unroll
    for (int j = 0; j < 4; ++j) { ac[j] = sm[64+c0+j]; bc4[j] = bp[c0+j]; }
    #pragma unroll
    for (int i = 0; i < 4; ++i)
      #pragma unroll
      for (int j = 0; j < 4; ++j)
        s2[i][j] += ar[i]*bc4[j] + br[i]*ac[j] + 32768.f*br[i]*bc4[j];
  }
  #pragma unroll
  for (int i = 0; i < 4; ++i)
    *(float4*)&s2p[(size_t)p * 4160 + (r0+i)*64 + c0] =
        make_float4(s2[i][0], s2[i][1], s2[i][2], s2[i][3]);
}

// k_small2: S2 = sum_p s2_p, then the serial chain -> Wo, bo
__global__ void __launch_bounds__(256) k_small2(
    const float* __restrict__ s2p,
    const float* __restrict__ qb_, const float* __restrict__ kb_,
    const float* __restrict__ vb_,
    const float* __restrict__ tk, const float* __restrict__ tv_,
    const float* __restrict__ tq, const float* __restrict__ lw,
    const float* __restrict__ lb_, const float* __restrict__ vw,
    float* __restrict__ wobo)
{
  __shared__ float BA[64][68];
  __shared__ float BB[64][68];
  __shared__ float BC[64][68];
  __shared__ float sm[512];   // 256:sum_s 320:w1 384:lb1 448:tvs
  const int tid = threadIdx.x;
  const int r0 = (tid >> 4) << 2;
  const int c0 = (tid & 15) << 2;

  for (int i = tid; i < 1024; i += 256) {
    int r_ = i >> 4, c_ = (i & 15) << 2;
    float4 v0 = ((const float4*)(s2p))[i];
    float4 v1 = ((const float4*)(s2p + 4160))[i];
    float4 v2 = ((const float4*)(s2p + 8320))[i];
    *(float4*)&BA[r_][c_] = make_float4(v0.x+v1.x+v2.x, v0.y+v1.y+v2.y,
                                        v0.z+v1.z+v2.z, v0.w+v1.w+v2.w);
  }
  STAGE_N(BC, tk);
  if (tid < 64) {
    float ss = s2p[4096 + tid] + s2p[4160 + 4096 + tid] + s2p[8320 + 4096 + tid]
             + 32768.f * (qb_[tid] + kb_[tid] + vb_[tid]);
    sm[256 + tid] = ss;
  }
  __syncthreads();
  if (tid < 64) {                          // w1 = t_k^T sum_s
    float s = 0.f;
    for (int k = 0; k < 64; ++k) s += BC[k][tid] * sm[256+k];
    sm[320 + tid] = s;
  }
  float y4[4][4] = {{0.f}};
  MM_TILE(y4, BA, BC, +=);                 // Y = S2 @ t_k
  __syncthreads();
  #pragma unroll
  for (int i = 0; i < 4; ++i)
    #pragma unroll
    for (int j = 0; j < 4; ++j) BB[r0+i][c0+j] = y4[i][j];       // Y
  STAGE_N(BA, tv_);                        // t_v (S2 dead)
  __syncthreads();
  if (tid < 64) {                          // tvs = t_v^T sum_s
    float s = 0.f;
    for (int k = 0; k < 64; ++k) s += BA[k][tid] * sm[256+k];
    sm[448 + tid] = s;
  }
  float core[4][4] = {{0.f}}, z4[4][4] = {{0.f}};
  for (int k = 0; k < 64; ++k) {           // core = -t_v^T Y ; Z = t_k^T Y
    float4 av1 = *(const float4*)&BA[k][r0];
    float4 av2 = *(const float4*)&BC[k][r0];
    float4 bv  = *(const float4*)&BB[k][c0];
    float a1_[4] = {av1.x,av1.y,av1.z,av1.w};
    float a2_[4] = {av2.x,av2.y,av2.z,av2.w};
    float b_[4]  = {bv.x,bv.y,bv.z,bv.w};
    #pragma unroll
    for (int i = 0; i < 4; ++i)
      #pragma unroll
      for (int j = 0; j < 4; ++j) { core[i][j] -= a1_[i]*b_[j]; z4[i][j] += a2_[i]*b_[j]; }
  }
  __syncthreads();
  #pragma unroll
  for (int i = 0; i < 4; ++i)
    #pragma unroll
    for (int j = 0; j < 4; ++j) BA[r0+i][c0+j] = z4[i][j];       // Z
  STAGE_T(BC, lw);                         // BC[k][r] = lw[r][k]
  __syncthreads();
  MM_TILE(core, BC, BA, +=);               // core += lw @ Z
  const float cg = 2.0f / 6291456.0f;      // 2 / (3B*64)
  float l1t[4][4];
  #pragma unroll
  for (int i = 0; i < 4; ++i) {
    float lbi = lb_[r0+i];
    #pragma unroll
    for (int j = 0; j < 4; ++j) {
      float gw  = cg * (core[i][j] + lbi * sm[320 + c0 + j]);
      float lwv = lw[(r0+i)*64 + (c0+j)];
      l1t[i][j] = lwv - 0.01f * gw / (fabsf(gw) + 1e-8f);
    }
  }
  __syncthreads();
  #pragma unroll
  for (int i = 0; i < 4; ++i)
    #pragma unroll
    for (int j = 0; j < 4; ++j) BB[c0+j][r0+i] = l1t[i][j];      // lw1^T
  if (tid < 64) {                          // gb -> lb1
    float s = 0.f;
    for (int c = 0; c < 64; ++c) s += lw[tid*64 + c] * sm[320 + c];
    float gb = cg * (s - sm[448 + tid] + 98304.f * lb_[tid]);
    sm[384 + tid] = lb_[tid] - 0.01f * gb / (fabsf(gb) + 1e-8f);
  }
  STAGE_T(BC, tq);                         // BC[k][r] = tq[r][k]
  __syncthreads();
  float u4[4][4] = {{0.f}};
  MM_TILE(u4, BC, BB, +=);                 // U = t_q @ lw1^T
  __syncthreads();
  #pragma unroll
  for (int i = 0; i < 4; ++i)
    #pragma unroll
    for (int j = 0; j < 4; ++j) BA[r0+i][c0+j] = u4[i][j];       // U
  STAGE_N(BC, vw);                         // v_w normal
  __syncthreads();
  float w4[4][4] = {{0.f}};
  MM_TILE(w4, BC, BA, +=);                 // Wo = v_w^T @ U
  #pragma unroll
  for (int i = 0; i < 4; ++i)
    *(float4*)&wobo[(r0+i)*64 + c0] = make_float4(w4[i][0], w4[i][1], w4[i][2], w4[i][3]);
  if (tid < 64) {                          // bo = v_b @ U + lb1
    float s = 0.f;
    for (int a = 0; a < 64; ++a) s += vb_[a] * BA[a][tid];
    wobo[4096 + tid] = s + sm[384 + tid];
  }
}

// ---------------- k_out: o = h@Wo + bo; LN; SiLU; dot(out_w) ----------------
__global__ void __launch_bounds__(128) k_out(
    const float* __restrict__ h, const float* __restrict__ wobo,
    const float* __restrict__ lng, const float* __restrict__ lnb,
    const float* __restrict__ outw, const float* __restrict__ outb,
    float* __restrict__ out)
{
  const size_t b = (size_t)blockIdx.x * 128 + threadIdx.x;
  const float* hr = h + b * 64;
  float o[64];
  #pragma unroll
  for (int j = 0; j < 64; ++j) o[j] = wobo[4096 + j];
  #pragma unroll 1
  for (int i = 0; i < 64; i += 4) {
    float4 hv = *(const float4*)(hr + i);
    const float* wr0 = wobo + (i+0)*64;
    const float* wr1 = wobo + (i+1)*64;
    const float* wr2 = wobo + (i+2)*64;
    const float* wr3 = wobo + (i+3)*64;
    #pragma unroll
    for (int j = 0; j < 64; ++j) o[j] += hv.x * wr0[j];
    #pragma unroll
    for (int j = 0; j < 64; ++j) o[j] += hv.y * wr1[j];
    #pragma unroll
    for (int j = 0; j < 64; ++j) o[j] += hv.z * wr2[j];
    #pragma unroll
    for (int j = 0; j < 64; ++j) o[j] += hv.w * wr3[j];
  }
  float mu = 0.f;
  #pragma unroll
  for (int j = 0; j < 64; ++j) mu += o[j];
  mu *= (1.0f/64.0f);
  float var = 0.f;
  #pragma unroll
  for (int j = 0; j < 64; ++j) { float d = o[j] - mu; var += d*d; }
  var *= (1.0f/64.0f);
  float inv = rsqrtf(var + 1e-5f);
  float accv = outb[0];
  #pragma unroll
  for (int j = 0; j < 64; ++j) {
    float n = (o[j] - mu) * inv * lng[j] + lnb[j];
    float a = n / (1.0f + __expf(-n));
    accv += a * outw[j];
  }
  out[b] = accv;
}

// ---------------------------------------------------------------------------
extern "C" void kernel_launch(void* const* d_in, const int* in_sizes, int n_in,
                              void* d_out, int out_size, void* d_ws, size_t ws_size,
                              hipStream_t stream) {
  const float* in1  = (const float*)d_in[0];
  const float* in2  = (const float*)d_in[1];
  const float* in3  = (const float*)d_in[2];
  const float* in4  = (const float*)d_in[3];
  const float* w_l  = (const float*)d_in[4];
  const float* b_l  = (const float*)d_in[5];
  const float* w_m  = (const float*)d_in[6];
  const float* b_m  = (const float*)d_in[7];
  const float* w_s  = (const float*)d_in[8];
  const float* b_s  = (const float*)d_in[9];
  const float* fc1w = (const float*)d_in[10];
  const float* fc1b = (const float*)d_in[11];
  const float* q_w  = (const float*)d_in[12];
  const float* q_b  = (const float*)d_in[13];
  const float* k_w  = (const float*)d_in[14];
  const float* k_b  = (const float*)d_in[15];
  const float* v_w  = (const float*)d_in[16];
  const float* v_b  = (const float*)d_in[17];
  const float* t_k  = (const float*)d_in[18];
  const float* t_v  = (const float*)d_in[19];
  const float* t_q  = (const float*)d_in[20];
  const float* lw   = (const float*)d_in[21];
  const float* lb   = (const float*)d_in[22];
  const float* ln_g = (const float*)d_in[23];
  const float* ln_b = (const float*)d_in[24];
  const float* outw = (const float*)d_in[25];
  const float* outb = (const float*)d_in[26];

  float* ws    = (float*)d_ws;
  float* WT    = ws;                      // 7200
  float* H     = ws + 7200;               // 32768*64 = 2097152
  float* PART  = H + 2097152;             // 256*4160 = 1064960
  float* PART2 = PART + 1064960;          // 8*4160 = 33280
  float* S2P   = PART2 + 33280;           // 3*4160 = 12480
  float* WOBO  = S2P + 12480;             // 4160 (Wo + bo)

  k_prep  <<<29,   256, 0, stream>>>(w_l, w_m, w_s, WT);
  k_front <<<2048, 256, 0, stream>>>(in1, in2, in3, in4, b_l, b_m, b_s,
                                     fc1w, fc1b, WT, H);
  k_gram  <<<256,  256, 0, stream>>>(H, PART);
  k_gred1 <<<136,  256, 0, stream>>>(PART, PART2);
  k_small1<<<3,    256, 0, stream>>>(PART2, q_w, q_b, k_w, k_b, v_w, v_b, S2P);
  k_small2<<<1,    256, 0, stream>>>(S2P, q_b, k_b, v_b, t_k, t_v, t_q,
                                     lw, lb, v_w, WOBO);
  k_out   <<<256,  128, 0, stream>>>(H, WOBO, ln_g, ln_b, outw, outb,
                                     (float*)d_out);
}